// Round 1
// baseline (480.553 us; speedup 1.0000x reference)
//
#include <hip/hip_runtime.h>
#include <hip/hip_bf16.h>
#include <cstdint>
#include <cstddef>

// ---------------- CSR construction ----------------

__global__ void count_edges_kernel(const int* __restrict__ dst, int* __restrict__ cnt, int E) {
  int e = blockIdx.x * blockDim.x + threadIdx.x;
  if (e < E) atomicAdd(&cnt[dst[e]], 1);
}

// Single-block scan: exclusive prefix of cnt -> rp, plus dis = rsqrt(deg) (deg = cnt+1 self-loop)
__global__ __launch_bounds__(1024) void scan_kernel(const int* __restrict__ cnt,
                                                    int* __restrict__ rp,
                                                    float* __restrict__ dis,
                                                    int N, int E) {
  __shared__ int wtot[16], wexc[16];
  __shared__ int s_run, s_chunk;
  const int tid = threadIdx.x, lane = tid & 63, wid = tid >> 6;
  if (tid == 0) s_run = 0;
  __syncthreads();
  for (int base = 0; base < N; base += 8192) {
    int v[8];
    int s = 0;
    const int i0 = base + tid * 8;
#pragma unroll
    for (int q = 0; q < 8; ++q) { int i = i0 + q; int x = (i < N) ? cnt[i] : 0; v[q] = x; s += x; }
    int sc = s;
#pragma unroll
    for (int off = 1; off < 64; off <<= 1) { int t = __shfl_up(sc, off); if (lane >= off) sc += t; }
    if (lane == 63) wtot[wid] = sc;
    __syncthreads();
    if (wid == 0) {
      int wv = (lane < 16) ? wtot[lane] : 0;
      int wsc = wv;
#pragma unroll
      for (int off = 1; off < 16; off <<= 1) { int t = __shfl_up(wsc, off); if (lane >= off) wsc += t; }
      if (lane < 16) wexc[lane] = wsc - wv;
      if (lane == 15) s_chunk = wsc;
    }
    __syncthreads();
    int thr = s_run + wexc[wid] + (sc - s);
#pragma unroll
    for (int q = 0; q < 8; ++q) {
      int i = i0 + q;
      if (i < N) { rp[i] = thr; dis[i] = rsqrtf((float)(v[q] + 1)); }
      thr += v[q];
    }
    __syncthreads();
    if (tid == 0) s_run += s_chunk;
    __syncthreads();
  }
  if (tid == 0) rp[N] = E;
}

__global__ void scatter_kernel(const int* __restrict__ src, const int* __restrict__ dst,
                               const int* __restrict__ rp, int* __restrict__ cur,
                               int* __restrict__ ss, int E) {
  int e = blockIdx.x * blockDim.x + threadIdx.x;
  if (e < E) {
    int d = dst[e];
    int pos = rp[d] + atomicAdd(&cur[d], 1);
    ss[pos] = src[e];
  }
}

// ---------------- GEMM: g[i,:] = dis[i] * (X[i,:] @ W), K = 128 ----------------

template <int COUT>
__global__ __launch_bounds__(256) void gemm_scale_kernel(const float* __restrict__ X,
                                                         const float* __restrict__ W,
                                                         const float* __restrict__ dis,
                                                         float* __restrict__ G, int N) {
  constexpr int BM = 64, BK = 32, K = 128;
  constexpr int CG = COUT / 8;    // col groups (each thread: 2 strips of 4 cols)
  constexpr int RPT = COUT / 32;  // rows per thread
  __shared__ float sX[BM][BK + 4];
  __shared__ float sW[BK][COUT];
  const int tid = threadIdx.x;
  const int row0 = blockIdx.x * BM;
  const int tc = tid % CG;
  const int tr = tid / CG;

  float acc[RPT][8];
#pragma unroll
  for (int r = 0; r < RPT; ++r)
#pragma unroll
    for (int j = 0; j < 8; ++j) acc[r][j] = 0.f;

  for (int ko = 0; ko < K; ko += BK) {
    // stage X tile: 64 rows x 32 k
    {
      const int lr0 = tid / 8;
      const int lc = tid % 8;
#pragma unroll
      for (int it = 0; it < 2; ++it) {
        int lr = lr0 + it * 32;
        int gr = row0 + lr;
        float4 val = make_float4(0.f, 0.f, 0.f, 0.f);
        if (gr < N) val = *(const float4*)&X[(size_t)gr * K + ko + lc * 4];
        *(float4*)&sX[lr][lc * 4] = val;
      }
    }
    // stage W tile: 32 k x COUT
    {
      constexpr int TOT = BK * COUT / 4;
#pragma unroll
      for (int it = 0; it < TOT / 256; ++it) {
        int fid = tid + it * 256;
        int kk = fid / (COUT / 4);
        int cc = fid % (COUT / 4);
        *(float4*)&sW[kk][cc * 4] = *(const float4*)&W[(size_t)(ko + kk) * COUT + cc * 4];
      }
    }
    __syncthreads();
#pragma unroll
    for (int k = 0; k < BK; k += 4) {
      float4 xv[RPT];
#pragma unroll
      for (int r = 0; r < RPT; ++r) xv[r] = *(const float4*)&sX[tr * RPT + r][k];
#pragma unroll
      for (int kk = 0; kk < 4; ++kk) {
        float4 w0 = *(const float4*)&sW[k + kk][tc * 4];
        float4 w1 = *(const float4*)&sW[k + kk][tc * 4 + COUT / 2];
#pragma unroll
        for (int r = 0; r < RPT; ++r) {
          float xs = ((const float*)&xv[r])[kk];
          acc[r][0] += xs * w0.x; acc[r][1] += xs * w0.y;
          acc[r][2] += xs * w0.z; acc[r][3] += xs * w0.w;
          acc[r][4] += xs * w1.x; acc[r][5] += xs * w1.y;
          acc[r][6] += xs * w1.z; acc[r][7] += xs * w1.w;
        }
      }
    }
    __syncthreads();
  }
#pragma unroll
  for (int r = 0; r < RPT; ++r) {
    int row = row0 + tr * RPT + r;
    if (row < N) {
      float sc = dis[row];
      float4 o0 = make_float4(acc[r][0] * sc, acc[r][1] * sc, acc[r][2] * sc, acc[r][3] * sc);
      float4 o1 = make_float4(acc[r][4] * sc, acc[r][5] * sc, acc[r][6] * sc, acc[r][7] * sc);
      *(float4*)&G[(size_t)row * COUT + tc * 4] = o0;
      *(float4*)&G[(size_t)row * COUT + tc * 4 + COUT / 2] = o1;
    }
  }
}

// ---------------- Aggregation: out[i] = dis[i]*(g[i] + sum g[src]) + b, opt ReLU ----------------

template <int F, bool RELU>
__global__ __launch_bounds__(256) void aggregate_kernel(const float* __restrict__ G,
                                                        const int* __restrict__ rp,
                                                        const int* __restrict__ ss,
                                                        const float* __restrict__ dis,
                                                        const float* __restrict__ bias,
                                                        float* __restrict__ OUT, int N) {
  const int w = blockIdx.x * (blockDim.x >> 6) + (threadIdx.x >> 6);
  const int lane = threadIdx.x & 63;
  if (w >= N) return;
  const int e0 = rp[w], e1 = rp[w + 1];
  if constexpr (F == 128) {
    float2 a = ((const float2*)(G + (size_t)w * F))[lane];
    for (int e = e0; e < e1; ++e) {
      int j = ss[e];
      float2 gv = ((const float2*)(G + (size_t)j * F))[lane];
      a.x += gv.x; a.y += gv.y;
    }
    float d = dis[w];
    float2 b = ((const float2*)bias)[lane];
    float ox = d * a.x + b.x, oy = d * a.y + b.y;
    if (RELU) { ox = fmaxf(ox, 0.f); oy = fmaxf(oy, 0.f); }
    ((float2*)(OUT + (size_t)w * F))[lane] = make_float2(ox, oy);
  } else {
    float a = G[(size_t)w * F + lane];
    for (int e = e0; e < e1; ++e) {
      int j = ss[e];
      a += G[(size_t)j * F + lane];
    }
    float d = dis[w];
    float o = d * a + bias[lane];
    if (RELU) o = fmaxf(o, 0.f);
    OUT[(size_t)w * F + lane] = o;
  }
}

// ---------------- launch ----------------

extern "C" void kernel_launch(void* const* d_in, const int* in_sizes, int n_in,
                              void* d_out, int out_size, void* d_ws, size_t ws_size,
                              hipStream_t stream) {
  const float* x  = (const float*)d_in[0];
  const int*   ei = (const int*)d_in[1];
  const float* W1 = (const float*)d_in[2];
  const float* b1 = (const float*)d_in[3];
  const float* W2 = (const float*)d_in[4];
  const float* b2 = (const float*)d_in[5];
  const float* W3 = (const float*)d_in[6];
  const float* b3 = (const float*)d_in[7];

  const int inC = in_sizes[2] / in_sizes[3];  // 128
  const int N = in_sizes[0] / inC;            // 50000
  const int E = in_sizes[1] / 2;              // 800000

  auto align256 = [](size_t v) { return (v + 255) & ~(size_t)255; };
  char* p = (char*)d_ws;
  int* cnt = (int*)p;   p += align256((size_t)N * 4);
  int* rp  = (int*)p;   p += align256((size_t)(N + 1) * 4);
  int* ss  = (int*)p;   p += align256((size_t)E * 4);
  float* dis = (float*)p; p += align256((size_t)N * 4);
  float* g = (float*)p;   p += align256((size_t)N * 128 * 4);
  float* h = (float*)p;   p += align256((size_t)N * 128 * 4);

  const int* srcv = ei;
  const int* dstv = ei + E;

  hipMemsetAsync(cnt, 0, (size_t)N * 4, stream);
  count_edges_kernel<<<(E + 255) / 256, 256, 0, stream>>>(dstv, cnt, E);
  scan_kernel<<<1, 1024, 0, stream>>>(cnt, rp, dis, N, E);
  hipMemsetAsync(cnt, 0, (size_t)N * 4, stream);
  scatter_kernel<<<(E + 255) / 256, 256, 0, stream>>>(srcv, dstv, rp, cnt, ss, E);

  const int gB = (N + 63) / 64;
  const int aB = (N + 3) / 4;

  // layer 1: 128 -> 128, relu
  gemm_scale_kernel<128><<<gB, 256, 0, stream>>>(x, W1, dis, g, N);
  aggregate_kernel<128, true><<<aB, 256, 0, stream>>>(g, rp, ss, dis, b1, h, N);
  // layer 2: 128 -> 128, relu
  gemm_scale_kernel<128><<<gB, 256, 0, stream>>>(h, W2, dis, g, N);
  aggregate_kernel<128, true><<<aB, 256, 0, stream>>>(g, rp, ss, dis, b2, h, N);
  // layer 3: 128 -> 64, no relu
  gemm_scale_kernel<64><<<gB, 256, 0, stream>>>(h, W3, dis, g, N);
  aggregate_kernel<64, false><<<aB, 256, 0, stream>>>(g, rp, ss, dis, b3, (float*)d_out, N);
}

// Round 2
// 356.357 us; speedup vs baseline: 1.3485x; 1.3485x over previous
//
#include <hip/hip_runtime.h>
#include <hip/hip_bf16.h>
#include <hip/hip_fp16.h>
#include <cstdint>
#include <cstddef>

struct alignas(8) half4 { __half2 lo, hi; };

// ---------------- CSR construction ----------------

__global__ void count_edges_kernel(const int* __restrict__ dst, int* __restrict__ cnt, int E) {
  int e = blockIdx.x * blockDim.x + threadIdx.x;
  if (e < E) atomicAdd(&cnt[dst[e]], 1);
}

// Single-block scan: exclusive prefix of cnt -> rp, plus dis = rsqrt(deg) (deg = cnt+1 self-loop)
__global__ __launch_bounds__(1024) void scan_kernel(const int* __restrict__ cnt,
                                                    int* __restrict__ rp,
                                                    float* __restrict__ dis,
                                                    int N, int E) {
  __shared__ int wtot[16], wexc[16];
  __shared__ int s_run, s_chunk;
  const int tid = threadIdx.x, lane = tid & 63, wid = tid >> 6;
  if (tid == 0) s_run = 0;
  __syncthreads();
  for (int base = 0; base < N; base += 8192) {
    int v[8];
    int s = 0;
    const int i0 = base + tid * 8;
#pragma unroll
    for (int q = 0; q < 8; ++q) { int i = i0 + q; int x = (i < N) ? cnt[i] : 0; v[q] = x; s += x; }
    int sc = s;
#pragma unroll
    for (int off = 1; off < 64; off <<= 1) { int t = __shfl_up(sc, off); if (lane >= off) sc += t; }
    if (lane == 63) wtot[wid] = sc;
    __syncthreads();
    if (wid == 0) {
      int wv = (lane < 16) ? wtot[lane] : 0;
      int wsc = wv;
#pragma unroll
      for (int off = 1; off < 16; off <<= 1) { int t = __shfl_up(wsc, off); if (lane >= off) wsc += t; }
      if (lane < 16) wexc[lane] = wsc - wv;
      if (lane == 15) s_chunk = wsc;
    }
    __syncthreads();
    int thr = s_run + wexc[wid] + (sc - s);
#pragma unroll
    for (int q = 0; q < 8; ++q) {
      int i = i0 + q;
      if (i < N) { rp[i] = thr; dis[i] = rsqrtf((float)(v[q] + 1)); }
      thr += v[q];
    }
    __syncthreads();
    if (tid == 0) s_run += s_chunk;
    __syncthreads();
  }
  if (tid == 0) rp[N] = E;
}

__global__ void scatter_kernel(const int* __restrict__ src, const int* __restrict__ dst,
                               const int* __restrict__ rp, int* __restrict__ cur,
                               int* __restrict__ ss, int E) {
  int e = blockIdx.x * blockDim.x + threadIdx.x;
  if (e < E) {
    int d = dst[e];
    int pos = rp[d] + atomicAdd(&cur[d], 1);
    ss[pos] = src[e];
  }
}

// ---------------- GEMM: g[i,:] = half( dis[i] * (X[i,:] @ W) ), K = 128 ----------------

template <int COUT>
__global__ __launch_bounds__(256) void gemm_scale_kernel(const float* __restrict__ X,
                                                         const float* __restrict__ W,
                                                         const float* __restrict__ dis,
                                                         __half* __restrict__ G, int N) {
  constexpr int BM = 128, BK = 32, K = 128;
  constexpr int CG = COUT / 8;    // col groups: 16 (COUT=128) or 8 (COUT=64)
  constexpr int RT = 256 / CG;    // row-thread count: 16 or 32
  constexpr int RPT = BM / RT;    // rows per thread: 8 or 4
  __shared__ float sX[BM][BK + 4];
  __shared__ float sW[BK][COUT];
  const int tid = threadIdx.x;
  const int row0 = blockIdx.x * BM;
  const int tc = tid % CG;
  const int tr = tid / CG;

  float acc[RPT][8];
#pragma unroll
  for (int r = 0; r < RPT; ++r)
#pragma unroll
    for (int j = 0; j < 8; ++j) acc[r][j] = 0.f;

  for (int ko = 0; ko < K; ko += BK) {
    // stage X tile: BM rows x 32 k  (BM/32 float4 per thread)
    {
      const int lr0 = tid / 8;
      const int lc = tid % 8;
#pragma unroll
      for (int it = 0; it < BM / 32; ++it) {
        int lr = lr0 + it * 32;
        int gr = row0 + lr;
        float4 val = make_float4(0.f, 0.f, 0.f, 0.f);
        if (gr < N) val = *(const float4*)&X[(size_t)gr * K + ko + lc * 4];
        *(float4*)&sX[lr][lc * 4] = val;
      }
    }
    // stage W tile: 32 k x COUT
    {
      constexpr int TOT = BK * COUT / 4;
#pragma unroll
      for (int it = 0; it < TOT / 256; ++it) {
        int fid = tid + it * 256;
        int kk = fid / (COUT / 4);
        int cc = fid % (COUT / 4);
        *(float4*)&sW[kk][cc * 4] = *(const float4*)&W[(size_t)(ko + kk) * COUT + cc * 4];
      }
    }
    __syncthreads();
#pragma unroll
    for (int k = 0; k < BK; k += 4) {
      float4 xv[RPT];
#pragma unroll
      for (int r = 0; r < RPT; ++r) xv[r] = *(const float4*)&sX[tr * RPT + r][k];
#pragma unroll
      for (int kk = 0; kk < 4; ++kk) {
        float4 w0 = *(const float4*)&sW[k + kk][tc * 4];
        float4 w1 = *(const float4*)&sW[k + kk][tc * 4 + COUT / 2];
#pragma unroll
        for (int r = 0; r < RPT; ++r) {
          float xs = ((const float*)&xv[r])[kk];
          acc[r][0] += xs * w0.x; acc[r][1] += xs * w0.y;
          acc[r][2] += xs * w0.z; acc[r][3] += xs * w0.w;
          acc[r][4] += xs * w1.x; acc[r][5] += xs * w1.y;
          acc[r][6] += xs * w1.z; acc[r][7] += xs * w1.w;
        }
      }
    }
    __syncthreads();
  }
#pragma unroll
  for (int r = 0; r < RPT; ++r) {
    int row = row0 + tr * RPT + r;
    if (row < N) {
      float sc = dis[row];
      half4 o0, o1;
      o0.lo = __floats2half2_rn(acc[r][0] * sc, acc[r][1] * sc);
      o0.hi = __floats2half2_rn(acc[r][2] * sc, acc[r][3] * sc);
      o1.lo = __floats2half2_rn(acc[r][4] * sc, acc[r][5] * sc);
      o1.hi = __floats2half2_rn(acc[r][6] * sc, acc[r][7] * sc);
      *(half4*)&G[(size_t)row * COUT + tc * 4] = o0;
      *(half4*)&G[(size_t)row * COUT + tc * 4 + COUT / 2] = o1;
    }
  }
}

// ---------------- Aggregation: out[i] = dis[i]*(g[i] + sum g[src]) + b, opt ReLU ----------------
// g is fp16 (pre-scaled by dis[src]); accumulate fp32; output fp32.

template <bool RELU>
__global__ __launch_bounds__(256) void aggregate128_kernel(const __half2* __restrict__ G,
                                                           const int* __restrict__ rp,
                                                           const int* __restrict__ ss,
                                                           const float* __restrict__ dis,
                                                           const float* __restrict__ bias,
                                                           float* __restrict__ OUT, int N) {
  const int w = blockIdx.x * (blockDim.x >> 6) + (threadIdx.x >> 6);
  const int lane = threadIdx.x & 63;
  if (w >= N) return;
  const int e0 = rp[w], e1 = rp[w + 1];
  float2 a = __half22float2(G[(size_t)w * 64 + lane]);
  int e = e0;
  for (; e + 4 <= e1; e += 4) {
    int j0 = ss[e + 0], j1 = ss[e + 1], j2 = ss[e + 2], j3 = ss[e + 3];
    __half2 v0 = G[(size_t)j0 * 64 + lane];
    __half2 v1 = G[(size_t)j1 * 64 + lane];
    __half2 v2 = G[(size_t)j2 * 64 + lane];
    __half2 v3 = G[(size_t)j3 * 64 + lane];
    float2 f0 = __half22float2(v0), f1 = __half22float2(v1);
    float2 f2 = __half22float2(v2), f3 = __half22float2(v3);
    a.x += (f0.x + f1.x) + (f2.x + f3.x);
    a.y += (f0.y + f1.y) + (f2.y + f3.y);
  }
  for (; e < e1; ++e) {
    float2 f = __half22float2(G[(size_t)ss[e] * 64 + lane]);
    a.x += f.x; a.y += f.y;
  }
  float d = dis[w];
  float2 b = ((const float2*)bias)[lane];
  float ox = d * a.x + b.x, oy = d * a.y + b.y;
  if (RELU) { ox = fmaxf(ox, 0.f); oy = fmaxf(oy, 0.f); }
  ((float2*)(OUT + (size_t)w * 128))[lane] = make_float2(ox, oy);
}

template <bool RELU>
__global__ __launch_bounds__(256) void aggregate64_kernel(const __half* __restrict__ G,
                                                          const int* __restrict__ rp,
                                                          const int* __restrict__ ss,
                                                          const float* __restrict__ dis,
                                                          const float* __restrict__ bias,
                                                          float* __restrict__ OUT, int N) {
  const int w = blockIdx.x * (blockDim.x >> 6) + (threadIdx.x >> 6);
  const int lane = threadIdx.x & 63;
  if (w >= N) return;
  const int e0 = rp[w], e1 = rp[w + 1];
  float a = __half2float(G[(size_t)w * 64 + lane]);
  int e = e0;
  for (; e + 4 <= e1; e += 4) {
    int j0 = ss[e + 0], j1 = ss[e + 1], j2 = ss[e + 2], j3 = ss[e + 3];
    float f0 = __half2float(G[(size_t)j0 * 64 + lane]);
    float f1 = __half2float(G[(size_t)j1 * 64 + lane]);
    float f2 = __half2float(G[(size_t)j2 * 64 + lane]);
    float f3 = __half2float(G[(size_t)j3 * 64 + lane]);
    a += (f0 + f1) + (f2 + f3);
  }
  for (; e < e1; ++e) a += __half2float(G[(size_t)ss[e] * 64 + lane]);
  float d = dis[w];
  float o = d * a + bias[lane];
  if (RELU) o = fmaxf(o, 0.f);
  OUT[(size_t)w * 64 + lane] = o;
}

// ---------------- launch ----------------

extern "C" void kernel_launch(void* const* d_in, const int* in_sizes, int n_in,
                              void* d_out, int out_size, void* d_ws, size_t ws_size,
                              hipStream_t stream) {
  const float* x  = (const float*)d_in[0];
  const int*   ei = (const int*)d_in[1];
  const float* W1 = (const float*)d_in[2];
  const float* b1 = (const float*)d_in[3];
  const float* W2 = (const float*)d_in[4];
  const float* b2 = (const float*)d_in[5];
  const float* W3 = (const float*)d_in[6];
  const float* b3 = (const float*)d_in[7];

  const int inC = in_sizes[2] / in_sizes[3];  // 128
  const int N = in_sizes[0] / inC;            // 50000
  const int E = in_sizes[1] / 2;              // 800000

  auto align256 = [](size_t v) { return (v + 255) & ~(size_t)255; };
  char* p = (char*)d_ws;
  int* cnt = (int*)p;   p += align256((size_t)N * 4);
  int* rp  = (int*)p;   p += align256((size_t)(N + 1) * 4);
  int* ss  = (int*)p;   p += align256((size_t)E * 4);
  float* dis = (float*)p; p += align256((size_t)N * 4);
  __half* g = (__half*)p; p += align256((size_t)N * 128 * 2);
  float* h = (float*)p;   p += align256((size_t)N * 128 * 4);

  const int* srcv = ei;
  const int* dstv = ei + E;

  hipMemsetAsync(cnt, 0, (size_t)N * 4, stream);
  count_edges_kernel<<<(E + 255) / 256, 256, 0, stream>>>(dstv, cnt, E);
  scan_kernel<<<1, 1024, 0, stream>>>(cnt, rp, dis, N, E);
  hipMemsetAsync(cnt, 0, (size_t)N * 4, stream);
  scatter_kernel<<<(E + 255) / 256, 256, 0, stream>>>(srcv, dstv, rp, cnt, ss, E);

  const int gB = (N + 127) / 128;
  const int aB = (N + 3) / 4;

  // layer 1: 128 -> 128, relu
  gemm_scale_kernel<128><<<gB, 256, 0, stream>>>(x, W1, dis, g, N);
  aggregate128_kernel<true><<<aB, 256, 0, stream>>>((const __half2*)g, rp, ss, dis, b1, h, N);
  // layer 2: 128 -> 128, relu
  gemm_scale_kernel<128><<<gB, 256, 0, stream>>>(h, W2, dis, g, N);
  aggregate128_kernel<true><<<aB, 256, 0, stream>>>((const __half2*)g, rp, ss, dis, b2, h, N);
  // layer 3: 128 -> 64, no relu
  gemm_scale_kernel<64><<<gB, 256, 0, stream>>>(h, W3, dis, g, N);
  aggregate64_kernel<false><<<aB, 256, 0, stream>>>(g, rp, ss, dis, b3, (float*)d_out, N);
}

// Round 3
// 286.347 us; speedup vs baseline: 1.6782x; 1.2445x over previous
//
#include <hip/hip_runtime.h>
#include <hip/hip_bf16.h>
#include <hip/hip_fp16.h>
#include <cstdint>
#include <cstddef>

struct alignas(8) half4 { __half2 lo, hi; };

// ---------------- CSR construction ----------------

__global__ void count_edges_kernel(const int* __restrict__ dst, int* __restrict__ cnt, int E) {
  int e = blockIdx.x * blockDim.x + threadIdx.x;
  if (e < E) atomicAdd(&cnt[dst[e]], 1);
}

// Multi-block scan, phase A: per-block (2048 elems) reduce
__global__ __launch_bounds__(256) void block_sum_kernel(const int* __restrict__ cnt,
                                                        int* __restrict__ bsum, int N) {
  const int tid = threadIdx.x, lane = tid & 63, wid = tid >> 6;
  __shared__ int wt[4];
  int base = blockIdx.x * 2048 + tid * 8;
  int s = 0;
#pragma unroll
  for (int q = 0; q < 8; ++q) { int i = base + q; if (i < N) s += cnt[i]; }
#pragma unroll
  for (int off = 32; off; off >>= 1) s += __shfl_down(s, off);
  if (lane == 0) wt[wid] = s;
  __syncthreads();
  if (tid == 0) bsum[blockIdx.x] = wt[0] + wt[1] + wt[2] + wt[3];
}

// Phase B: single small block scans the block sums (NB <= 256), writes rp[N]=E
__global__ __launch_bounds__(256) void scan_bsum_kernel(const int* __restrict__ bsum,
                                                        int* __restrict__ boff,
                                                        int NB, int E, int* __restrict__ rpN) {
  __shared__ int sh[256];
  const int tid = threadIdx.x;
  int v = (tid < NB) ? bsum[tid] : 0;
  sh[tid] = v;
  __syncthreads();
  for (int off = 1; off < 256; off <<= 1) {
    int t = (tid >= off) ? sh[tid - off] : 0;
    __syncthreads();
    sh[tid] += t;
    __syncthreads();
  }
  if (tid < NB) boff[tid] = sh[tid] - v;
  if (tid == 0) rpN[0] = E;
}

// Phase C: per-block exclusive scan + global offset -> rp, dis
__global__ __launch_bounds__(256) void scan_apply_kernel(const int* __restrict__ cnt,
                                                         const int* __restrict__ boff,
                                                         int* __restrict__ rp,
                                                         float* __restrict__ dis, int N) {
  const int tid = threadIdx.x, lane = tid & 63, wid = tid >> 6;
  __shared__ int wtot[4], wexc[4];
  int base = blockIdx.x * 2048 + tid * 8;
  int v[8]; int s = 0;
#pragma unroll
  for (int q = 0; q < 8; ++q) { int i = base + q; int x = (i < N) ? cnt[i] : 0; v[q] = x; s += x; }
  int sc = s;
#pragma unroll
  for (int off = 1; off < 64; off <<= 1) { int t = __shfl_up(sc, off); if (lane >= off) sc += t; }
  if (lane == 63) wtot[wid] = sc;
  __syncthreads();
  if (tid == 0) { int r = 0; for (int wq = 0; wq < 4; ++wq) { wexc[wq] = r; r += wtot[wq]; } }
  __syncthreads();
  int thr = boff[blockIdx.x] + wexc[wid] + (sc - s);
#pragma unroll
  for (int q = 0; q < 8; ++q) {
    int i = base + q;
    if (i < N) { rp[i] = thr; dis[i] = rsqrtf((float)(v[q] + 1)); }
    thr += v[q];
  }
}

__global__ void scatter_kernel(const int* __restrict__ src, const int* __restrict__ dst,
                               const int* __restrict__ rp, int* __restrict__ cur,
                               int* __restrict__ ss, int E) {
  int e = blockIdx.x * blockDim.x + threadIdx.x;
  if (e < E) {
    int d = dst[e];
    int pos = rp[d] + atomicAdd(&cur[d], 1);
    ss[pos] = src[e];
  }
}

// ---------------- GEMM: g[i,:] = half( dis[i] * (X[i,:] @ W) ), K = 128 ----------------

template <int COUT>
__global__ __launch_bounds__(256) void gemm_scale_kernel(const float* __restrict__ X,
                                                         const float* __restrict__ W,
                                                         const float* __restrict__ dis,
                                                         __half* __restrict__ G, int N) {
  constexpr int BM = 128, BK = 32, K = 128;
  constexpr int CG = COUT / 8;
  constexpr int RT = 256 / CG;
  constexpr int RPT = BM / RT;
  __shared__ float sX[BM][BK + 4];
  __shared__ float sW[BK][COUT];
  const int tid = threadIdx.x;
  const int row0 = blockIdx.x * BM;
  const int tc = tid % CG;
  const int tr = tid / CG;

  float acc[RPT][8];
#pragma unroll
  for (int r = 0; r < RPT; ++r)
#pragma unroll
    for (int j = 0; j < 8; ++j) acc[r][j] = 0.f;

  for (int ko = 0; ko < K; ko += BK) {
    {
      const int lr0 = tid / 8;
      const int lc = tid % 8;
#pragma unroll
      for (int it = 0; it < BM / 32; ++it) {
        int lr = lr0 + it * 32;
        int gr = row0 + lr;
        float4 val = make_float4(0.f, 0.f, 0.f, 0.f);
        if (gr < N) val = *(const float4*)&X[(size_t)gr * K + ko + lc * 4];
        *(float4*)&sX[lr][lc * 4] = val;
      }
    }
    {
      constexpr int TOT = BK * COUT / 4;
#pragma unroll
      for (int it = 0; it < TOT / 256; ++it) {
        int fid = tid + it * 256;
        int kk = fid / (COUT / 4);
        int cc = fid % (COUT / 4);
        *(float4*)&sW[kk][cc * 4] = *(const float4*)&W[(size_t)(ko + kk) * COUT + cc * 4];
      }
    }
    __syncthreads();
#pragma unroll
    for (int k = 0; k < BK; k += 4) {
      float4 xv[RPT];
#pragma unroll
      for (int r = 0; r < RPT; ++r) xv[r] = *(const float4*)&sX[tr * RPT + r][k];
#pragma unroll
      for (int kk = 0; kk < 4; ++kk) {
        float4 w0 = *(const float4*)&sW[k + kk][tc * 4];
        float4 w1 = *(const float4*)&sW[k + kk][tc * 4 + COUT / 2];
#pragma unroll
        for (int r = 0; r < RPT; ++r) {
          float xs = ((const float*)&xv[r])[kk];
          acc[r][0] += xs * w0.x; acc[r][1] += xs * w0.y;
          acc[r][2] += xs * w0.z; acc[r][3] += xs * w0.w;
          acc[r][4] += xs * w1.x; acc[r][5] += xs * w1.y;
          acc[r][6] += xs * w1.z; acc[r][7] += xs * w1.w;
        }
      }
    }
    __syncthreads();
  }
#pragma unroll
  for (int r = 0; r < RPT; ++r) {
    int row = row0 + tr * RPT + r;
    if (row < N) {
      float sc = dis[row];
      half4 o0, o1;
      o0.lo = __floats2half2_rn(acc[r][0] * sc, acc[r][1] * sc);
      o0.hi = __floats2half2_rn(acc[r][2] * sc, acc[r][3] * sc);
      o1.lo = __floats2half2_rn(acc[r][4] * sc, acc[r][5] * sc);
      o1.hi = __floats2half2_rn(acc[r][6] * sc, acc[r][7] * sc);
      *(half4*)&G[(size_t)row * COUT + tc * 4] = o0;
      *(half4*)&G[(size_t)row * COUT + tc * 4 + COUT / 2] = o1;
    }
  }
}

// ---------------- Aggregation ----------------

template <bool RELU>
__global__ __launch_bounds__(256) void aggregate128_kernel(const __half2* __restrict__ G,
                                                           const int* __restrict__ rp,
                                                           const int* __restrict__ ss,
                                                           const float* __restrict__ dis,
                                                           const float* __restrict__ bias,
                                                           float* __restrict__ OUT, int N) {
  const int w = blockIdx.x * (blockDim.x >> 6) + (threadIdx.x >> 6);
  const int lane = threadIdx.x & 63;
  if (w >= N) return;
  const int e0 = rp[w], e1 = rp[w + 1];
  float2 a = __half22float2(G[(size_t)w * 64 + lane]);
  int e = e0;
  for (; e + 8 <= e1; e += 8) {
    int j[8];
#pragma unroll
    for (int q = 0; q < 8; ++q) j[q] = ss[e + q];
    float2 f[8];
#pragma unroll
    for (int q = 0; q < 8; ++q) f[q] = __half22float2(G[(size_t)j[q] * 64 + lane]);
#pragma unroll
    for (int q = 0; q < 8; ++q) { a.x += f[q].x; a.y += f[q].y; }
  }
  for (; e + 2 <= e1; e += 2) {
    int j0 = ss[e], j1 = ss[e + 1];
    float2 f0 = __half22float2(G[(size_t)j0 * 64 + lane]);
    float2 f1 = __half22float2(G[(size_t)j1 * 64 + lane]);
    a.x += f0.x + f1.x; a.y += f0.y + f1.y;
  }
  for (; e < e1; ++e) {
    float2 f = __half22float2(G[(size_t)ss[e] * 64 + lane]);
    a.x += f.x; a.y += f.y;
  }
  float d = dis[w];
  float2 b = ((const float2*)bias)[lane];
  float ox = d * a.x + b.x, oy = d * a.y + b.y;
  if (RELU) { ox = fmaxf(ox, 0.f); oy = fmaxf(oy, 0.f); }
  ((float2*)(OUT + (size_t)w * 128))[lane] = make_float2(ox, oy);
}

template <bool RELU>
__global__ __launch_bounds__(256) void aggregate64_kernel(const __half* __restrict__ G,
                                                          const int* __restrict__ rp,
                                                          const int* __restrict__ ss,
                                                          const float* __restrict__ dis,
                                                          const float* __restrict__ bias,
                                                          float* __restrict__ OUT, int N) {
  const int w = blockIdx.x * (blockDim.x >> 6) + (threadIdx.x >> 6);
  const int lane = threadIdx.x & 63;
  if (w >= N) return;
  const int e0 = rp[w], e1 = rp[w + 1];
  float a = __half2float(G[(size_t)w * 64 + lane]);
  int e = e0;
  for (; e + 8 <= e1; e += 8) {
    int j[8];
#pragma unroll
    for (int q = 0; q < 8; ++q) j[q] = ss[e + q];
    float f[8];
#pragma unroll
    for (int q = 0; q < 8; ++q) f[q] = __half2float(G[(size_t)j[q] * 64 + lane]);
    a += ((f[0] + f[1]) + (f[2] + f[3])) + ((f[4] + f[5]) + (f[6] + f[7]));
  }
  for (; e < e1; ++e) a += __half2float(G[(size_t)ss[e] * 64 + lane]);
  float d = dis[w];
  float o = d * a + bias[lane];
  if (RELU) o = fmaxf(o, 0.f);
  OUT[(size_t)w * 64 + lane] = o;
}

// ---------------- launch ----------------

extern "C" void kernel_launch(void* const* d_in, const int* in_sizes, int n_in,
                              void* d_out, int out_size, void* d_ws, size_t ws_size,
                              hipStream_t stream) {
  const float* x  = (const float*)d_in[0];
  const int*   ei = (const int*)d_in[1];
  const float* W1 = (const float*)d_in[2];
  const float* b1 = (const float*)d_in[3];
  const float* W2 = (const float*)d_in[4];
  const float* b2 = (const float*)d_in[5];
  const float* W3 = (const float*)d_in[6];
  const float* b3 = (const float*)d_in[7];

  const int inC = in_sizes[2] / in_sizes[3];  // 128
  const int N = in_sizes[0] / inC;            // 50000
  const int E = in_sizes[1] / 2;              // 800000

  auto align256 = [](size_t v) { return (v + 255) & ~(size_t)255; };
  char* p = (char*)d_ws;
  int* cnt = (int*)p;   p += align256((size_t)N * 4);
  int* rp  = (int*)p;   p += align256((size_t)(N + 1) * 4);
  int* ss  = (int*)p;   p += align256((size_t)E * 4);
  float* dis = (float*)p; p += align256((size_t)N * 4);
  __half* g = (__half*)p; p += align256((size_t)N * 128 * 2);
  float* h = (float*)p;   p += align256((size_t)N * 128 * 4);
  int* bsum = (int*)p;  p += align256(1024 * 4);
  int* boff = (int*)p;  p += align256(1024 * 4);

  const int* srcv = ei;
  const int* dstv = ei + E;

  const int NB = (N + 2047) / 2048;  // 25

  hipMemsetAsync(cnt, 0, (size_t)N * 4, stream);
  count_edges_kernel<<<(E + 255) / 256, 256, 0, stream>>>(dstv, cnt, E);
  block_sum_kernel<<<NB, 256, 0, stream>>>(cnt, bsum, N);
  scan_bsum_kernel<<<1, 256, 0, stream>>>(bsum, boff, NB, E, rp + N);
  scan_apply_kernel<<<NB, 256, 0, stream>>>(cnt, boff, rp, dis, N);
  hipMemsetAsync(cnt, 0, (size_t)N * 4, stream);
  scatter_kernel<<<(E + 255) / 256, 256, 0, stream>>>(srcv, dstv, rp, cnt, ss, E);

  const int gB = (N + 127) / 128;
  const int aB = (N + 3) / 4;

  // layer 1: 128 -> 128, relu
  gemm_scale_kernel<128><<<gB, 256, 0, stream>>>(x, W1, dis, g, N);
  aggregate128_kernel<true><<<aB, 256, 0, stream>>>((const __half2*)g, rp, ss, dis, b1, h, N);
  // layer 2: 128 -> 128, relu
  gemm_scale_kernel<128><<<gB, 256, 0, stream>>>(h, W2, dis, g, N);
  aggregate128_kernel<true><<<aB, 256, 0, stream>>>((const __half2*)g, rp, ss, dis, b2, h, N);
  // layer 3: 128 -> 64, no relu
  gemm_scale_kernel<64><<<gB, 256, 0, stream>>>(h, W3, dis, g, N);
  aggregate64_kernel<false><<<aB, 256, 0, stream>>>(g, rp, ss, dis, b3, (float*)d_out, N);
}

// Round 4
// 262.816 us; speedup vs baseline: 1.8285x; 1.0895x over previous
//
#include <hip/hip_runtime.h>
#include <hip/hip_bf16.h>
#include <hip/hip_fp16.h>
#include <cstdint>
#include <cstddef>

struct alignas(8) half4 { __half2 lo, hi; };

// ---------------- CSR construction ----------------

// Fused count + position: pos[e] = old count of dst[e]. 4 edges/thread for ILP.
__global__ __launch_bounds__(256) void countpos_kernel(const int* __restrict__ dst,
                                                       int* __restrict__ cnt,
                                                       int* __restrict__ pos, int E) {
  int e = (blockIdx.x * blockDim.x + threadIdx.x) * 4;
  if (e + 4 <= E) {
    int4 d = *(const int4*)&dst[e];
    int p0 = atomicAdd(&cnt[d.x], 1);
    int p1 = atomicAdd(&cnt[d.y], 1);
    int p2 = atomicAdd(&cnt[d.z], 1);
    int p3 = atomicAdd(&cnt[d.w], 1);
    *(int4*)&pos[e] = make_int4(p0, p1, p2, p3);
  } else {
    for (; e < E; ++e) pos[e] = atomicAdd(&cnt[dst[e]], 1);
  }
}

// Atomic-free placement: ss[rp[dst]+pos] = src. 4 edges/thread.
__global__ __launch_bounds__(256) void place_kernel(const int* __restrict__ src,
                                                    const int* __restrict__ dst,
                                                    const int* __restrict__ pos,
                                                    const int* __restrict__ rp,
                                                    int* __restrict__ ss, int E) {
  int e = (blockIdx.x * blockDim.x + threadIdx.x) * 4;
  if (e + 4 <= E) {
    int4 d = *(const int4*)&dst[e];
    int4 p = *(const int4*)&pos[e];
    int4 s = *(const int4*)&src[e];
    int r0 = rp[d.x], r1 = rp[d.y], r2 = rp[d.z], r3 = rp[d.w];
    ss[r0 + p.x] = s.x;
    ss[r1 + p.y] = s.y;
    ss[r2 + p.z] = s.z;
    ss[r3 + p.w] = s.w;
  } else {
    for (; e < E; ++e) ss[rp[dst[e]] + pos[e]] = src[e];
  }
}

// Multi-block scan, phase A: per-block (2048 elems) reduce
__global__ __launch_bounds__(256) void block_sum_kernel(const int* __restrict__ cnt,
                                                        int* __restrict__ bsum, int N) {
  const int tid = threadIdx.x, lane = tid & 63, wid = tid >> 6;
  __shared__ int wt[4];
  int base = blockIdx.x * 2048 + tid * 8;
  int s = 0;
#pragma unroll
  for (int q = 0; q < 8; ++q) { int i = base + q; if (i < N) s += cnt[i]; }
#pragma unroll
  for (int off = 32; off; off >>= 1) s += __shfl_down(s, off);
  if (lane == 0) wt[wid] = s;
  __syncthreads();
  if (tid == 0) bsum[blockIdx.x] = wt[0] + wt[1] + wt[2] + wt[3];
}

// Phase B: single small block scans the block sums (NB <= 256), writes rp[N]=E
__global__ __launch_bounds__(256) void scan_bsum_kernel(const int* __restrict__ bsum,
                                                        int* __restrict__ boff,
                                                        int NB, int E, int* __restrict__ rpN) {
  __shared__ int sh[256];
  const int tid = threadIdx.x;
  int v = (tid < NB) ? bsum[tid] : 0;
  sh[tid] = v;
  __syncthreads();
  for (int off = 1; off < 256; off <<= 1) {
    int t = (tid >= off) ? sh[tid - off] : 0;
    __syncthreads();
    sh[tid] += t;
    __syncthreads();
  }
  if (tid < NB) boff[tid] = sh[tid] - v;
  if (tid == 0) rpN[0] = E;
}

// Phase C: per-block exclusive scan + global offset -> rp, dis
__global__ __launch_bounds__(256) void scan_apply_kernel(const int* __restrict__ cnt,
                                                         const int* __restrict__ boff,
                                                         int* __restrict__ rp,
                                                         float* __restrict__ dis, int N) {
  const int tid = threadIdx.x, lane = tid & 63, wid = tid >> 6;
  __shared__ int wtot[4], wexc[4];
  int base = blockIdx.x * 2048 + tid * 8;
  int v[8]; int s = 0;
#pragma unroll
  for (int q = 0; q < 8; ++q) { int i = base + q; int x = (i < N) ? cnt[i] : 0; v[q] = x; s += x; }
  int sc = s;
#pragma unroll
  for (int off = 1; off < 64; off <<= 1) { int t = __shfl_up(sc, off); if (lane >= off) sc += t; }
  if (lane == 63) wtot[wid] = sc;
  __syncthreads();
  if (tid == 0) { int r = 0; for (int wq = 0; wq < 4; ++wq) { wexc[wq] = r; r += wtot[wq]; } }
  __syncthreads();
  int thr = boff[blockIdx.x] + wexc[wid] + (sc - s);
#pragma unroll
  for (int q = 0; q < 8; ++q) {
    int i = base + q;
    if (i < N) { rp[i] = thr; dis[i] = rsqrtf((float)(v[q] + 1)); }
    thr += v[q];
  }
}

// ---------------- GEMM: g[i,:] = half( dis[i] * (X[i,:] @ W) ), K = 128 ----------------

template <int COUT>
__global__ __launch_bounds__(256) void gemm_scale_kernel(const float* __restrict__ X,
                                                         const float* __restrict__ W,
                                                         const float* __restrict__ dis,
                                                         __half* __restrict__ G, int N) {
  constexpr int BM = 128, BK = 32, K = 128;
  constexpr int CG = COUT / 8;
  constexpr int RT = 256 / CG;
  constexpr int RPT = BM / RT;
  __shared__ float sX[BM][BK + 4];
  __shared__ float sW[BK][COUT];
  const int tid = threadIdx.x;
  const int row0 = blockIdx.x * BM;
  const int tc = tid % CG;
  const int tr = tid / CG;

  float acc[RPT][8];
#pragma unroll
  for (int r = 0; r < RPT; ++r)
#pragma unroll
    for (int j = 0; j < 8; ++j) acc[r][j] = 0.f;

  for (int ko = 0; ko < K; ko += BK) {
    {
      const int lr0 = tid / 8;
      const int lc = tid % 8;
#pragma unroll
      for (int it = 0; it < BM / 32; ++it) {
        int lr = lr0 + it * 32;
        int gr = row0 + lr;
        float4 val = make_float4(0.f, 0.f, 0.f, 0.f);
        if (gr < N) val = *(const float4*)&X[(size_t)gr * K + ko + lc * 4];
        *(float4*)&sX[lr][lc * 4] = val;
      }
    }
    {
      constexpr int TOT = BK * COUT / 4;
#pragma unroll
      for (int it = 0; it < TOT / 256; ++it) {
        int fid = tid + it * 256;
        int kk = fid / (COUT / 4);
        int cc = fid % (COUT / 4);
        *(float4*)&sW[kk][cc * 4] = *(const float4*)&W[(size_t)(ko + kk) * COUT + cc * 4];
      }
    }
    __syncthreads();
#pragma unroll
    for (int k = 0; k < BK; k += 4) {
      float4 xv[RPT];
#pragma unroll
      for (int r = 0; r < RPT; ++r) xv[r] = *(const float4*)&sX[tr * RPT + r][k];
#pragma unroll
      for (int kk = 0; kk < 4; ++kk) {
        float4 w0 = *(const float4*)&sW[k + kk][tc * 4];
        float4 w1 = *(const float4*)&sW[k + kk][tc * 4 + COUT / 2];
#pragma unroll
        for (int r = 0; r < RPT; ++r) {
          float xs = ((const float*)&xv[r])[kk];
          acc[r][0] += xs * w0.x; acc[r][1] += xs * w0.y;
          acc[r][2] += xs * w0.z; acc[r][3] += xs * w0.w;
          acc[r][4] += xs * w1.x; acc[r][5] += xs * w1.y;
          acc[r][6] += xs * w1.z; acc[r][7] += xs * w1.w;
        }
      }
    }
    __syncthreads();
  }
#pragma unroll
  for (int r = 0; r < RPT; ++r) {
    int row = row0 + tr * RPT + r;
    if (row < N) {
      float sc = dis[row];
      half4 o0, o1;
      o0.lo = __floats2half2_rn(acc[r][0] * sc, acc[r][1] * sc);
      o0.hi = __floats2half2_rn(acc[r][2] * sc, acc[r][3] * sc);
      o1.lo = __floats2half2_rn(acc[r][4] * sc, acc[r][5] * sc);
      o1.hi = __floats2half2_rn(acc[r][6] * sc, acc[r][7] * sc);
      *(half4*)&G[(size_t)row * COUT + tc * 4] = o0;
      *(half4*)&G[(size_t)row * COUT + tc * 4 + COUT / 2] = o1;
    }
  }
}

// ---------------- Aggregation ----------------

template <bool RELU>
__global__ __launch_bounds__(256) void aggregate128_kernel(const __half2* __restrict__ G,
                                                           const int* __restrict__ rp,
                                                           const int* __restrict__ ss,
                                                           const float* __restrict__ dis,
                                                           const float* __restrict__ bias,
                                                           float* __restrict__ OUT, int N) {
  const int w = blockIdx.x * (blockDim.x >> 6) + (threadIdx.x >> 6);
  const int lane = threadIdx.x & 63;
  if (w >= N) return;
  const int e0 = rp[w], e1 = rp[w + 1];
  float2 a = __half22float2(G[(size_t)w * 64 + lane]);
  int e = e0;
  for (; e + 16 <= e1; e += 16) {
    int j[16];
#pragma unroll
    for (int q = 0; q < 16; ++q) j[q] = ss[e + q];
    float2 f[16];
#pragma unroll
    for (int q = 0; q < 16; ++q) f[q] = __half22float2(G[(size_t)j[q] * 64 + lane]);
#pragma unroll
    for (int q = 0; q < 16; ++q) { a.x += f[q].x; a.y += f[q].y; }
  }
  for (; e + 4 <= e1; e += 4) {
    int j[4];
#pragma unroll
    for (int q = 0; q < 4; ++q) j[q] = ss[e + q];
    float2 f[4];
#pragma unroll
    for (int q = 0; q < 4; ++q) f[q] = __half22float2(G[(size_t)j[q] * 64 + lane]);
#pragma unroll
    for (int q = 0; q < 4; ++q) { a.x += f[q].x; a.y += f[q].y; }
  }
  for (; e < e1; ++e) {
    float2 f = __half22float2(G[(size_t)ss[e] * 64 + lane]);
    a.x += f.x; a.y += f.y;
  }
  float d = dis[w];
  float2 b = ((const float2*)bias)[lane];
  float ox = d * a.x + b.x, oy = d * a.y + b.y;
  if (RELU) { ox = fmaxf(ox, 0.f); oy = fmaxf(oy, 0.f); }
  ((float2*)(OUT + (size_t)w * 128))[lane] = make_float2(ox, oy);
}

template <bool RELU>
__global__ __launch_bounds__(256) void aggregate64_kernel(const __half* __restrict__ G,
                                                          const int* __restrict__ rp,
                                                          const int* __restrict__ ss,
                                                          const float* __restrict__ dis,
                                                          const float* __restrict__ bias,
                                                          float* __restrict__ OUT, int N) {
  const int w = blockIdx.x * (blockDim.x >> 6) + (threadIdx.x >> 6);
  const int lane = threadIdx.x & 63;
  if (w >= N) return;
  const int e0 = rp[w], e1 = rp[w + 1];
  float a = __half2float(G[(size_t)w * 64 + lane]);
  int e = e0;
  for (; e + 16 <= e1; e += 16) {
    int j[16];
#pragma unroll
    for (int q = 0; q < 16; ++q) j[q] = ss[e + q];
    float f[16];
#pragma unroll
    for (int q = 0; q < 16; ++q) f[q] = __half2float(G[(size_t)j[q] * 64 + lane]);
#pragma unroll
    for (int q = 0; q < 16; ++q) a += f[q];
  }
  for (; e < e1; ++e) a += __half2float(G[(size_t)ss[e] * 64 + lane]);
  float d = dis[w];
  float o = d * a + bias[lane];
  if (RELU) o = fmaxf(o, 0.f);
  OUT[(size_t)w * 64 + lane] = o;
}

// ---------------- launch ----------------

extern "C" void kernel_launch(void* const* d_in, const int* in_sizes, int n_in,
                              void* d_out, int out_size, void* d_ws, size_t ws_size,
                              hipStream_t stream) {
  const float* x  = (const float*)d_in[0];
  const int*   ei = (const int*)d_in[1];
  const float* W1 = (const float*)d_in[2];
  const float* b1 = (const float*)d_in[3];
  const float* W2 = (const float*)d_in[4];
  const float* b2 = (const float*)d_in[5];
  const float* W3 = (const float*)d_in[6];
  const float* b3 = (const float*)d_in[7];

  const int inC = in_sizes[2] / in_sizes[3];  // 128
  const int N = in_sizes[0] / inC;            // 50000
  const int E = in_sizes[1] / 2;              // 800000

  auto align256 = [](size_t v) { return (v + 255) & ~(size_t)255; };
  char* p = (char*)d_ws;
  int* cnt = (int*)p;   p += align256((size_t)N * 4);
  int* rp  = (int*)p;   p += align256((size_t)(N + 1) * 4);
  int* ss  = (int*)p;   p += align256((size_t)E * 4);
  int* pos = (int*)p;   p += align256((size_t)E * 4);
  float* dis = (float*)p; p += align256((size_t)N * 4);
  __half* g = (__half*)p; p += align256((size_t)N * 128 * 2);
  float* h = (float*)p;   p += align256((size_t)N * 128 * 4);
  int* bsum = (int*)p;  p += align256(1024 * 4);
  int* boff = (int*)p;  p += align256(1024 * 4);

  const int* srcv = ei;
  const int* dstv = ei + E;

  const int NB = (N + 2047) / 2048;  // 25
  const int eB4 = (E / 4 + 255) / 256;

  hipMemsetAsync(cnt, 0, (size_t)N * 4, stream);
  countpos_kernel<<<eB4, 256, 0, stream>>>(dstv, cnt, pos, E);
  block_sum_kernel<<<NB, 256, 0, stream>>>(cnt, bsum, N);
  scan_bsum_kernel<<<1, 256, 0, stream>>>(bsum, boff, NB, E, rp + N);
  scan_apply_kernel<<<NB, 256, 0, stream>>>(cnt, boff, rp, dis, N);
  place_kernel<<<eB4, 256, 0, stream>>>(srcv, dstv, pos, rp, ss, E);

  const int gB = (N + 127) / 128;
  const int aB = (N + 3) / 4;

  // layer 1: 128 -> 128, relu
  gemm_scale_kernel<128><<<gB, 256, 0, stream>>>(x, W1, dis, g, N);
  aggregate128_kernel<true><<<aB, 256, 0, stream>>>((const __half2*)g, rp, ss, dis, b1, h, N);
  // layer 2: 128 -> 128, relu
  gemm_scale_kernel<128><<<gB, 256, 0, stream>>>(h, W2, dis, g, N);
  aggregate128_kernel<true><<<aB, 256, 0, stream>>>((const __half2*)g, rp, ss, dis, b2, h, N);
  // layer 3: 128 -> 64, no relu
  gemm_scale_kernel<64><<<gB, 256, 0, stream>>>(h, W3, dis, g, N);
  aggregate64_kernel<false><<<aB, 256, 0, stream>>>(g, rp, ss, dis, b3, (float*)d_out, N);
}

// Round 5
// 200.124 us; speedup vs baseline: 2.4013x; 1.3133x over previous
//
#include <hip/hip_runtime.h>
#include <hip/hip_bf16.h>
#include <hip/hip_fp16.h>
#include <cstdint>
#include <cstddef>

typedef _Float16 half8_t __attribute__((ext_vector_type(8)));
typedef float f32x4 __attribute__((ext_vector_type(4)));

// ---------------- CSR construction ----------------

__global__ __launch_bounds__(256) void countpos_kernel(const int* __restrict__ dst,
                                                       int* __restrict__ cnt,
                                                       int* __restrict__ pos, int E) {
  int e = (blockIdx.x * blockDim.x + threadIdx.x) * 4;
  if (e + 4 <= E) {
    int4 d = *(const int4*)&dst[e];
    int p0 = atomicAdd(&cnt[d.x], 1);
    int p1 = atomicAdd(&cnt[d.y], 1);
    int p2 = atomicAdd(&cnt[d.z], 1);
    int p3 = atomicAdd(&cnt[d.w], 1);
    *(int4*)&pos[e] = make_int4(p0, p1, p2, p3);
  } else {
    for (; e < E; ++e) pos[e] = atomicAdd(&cnt[dst[e]], 1);
  }
}

__global__ __launch_bounds__(256) void place_kernel(const int* __restrict__ src,
                                                    const int* __restrict__ dst,
                                                    const int* __restrict__ pos,
                                                    const int* __restrict__ rp,
                                                    int* __restrict__ ss, int E) {
  int e = (blockIdx.x * blockDim.x + threadIdx.x) * 4;
  if (e + 4 <= E) {
    int4 d = *(const int4*)&dst[e];
    int4 p = *(const int4*)&pos[e];
    int4 s = *(const int4*)&src[e];
    int r0 = rp[d.x], r1 = rp[d.y], r2 = rp[d.z], r3 = rp[d.w];
    ss[r0 + p.x] = s.x;
    ss[r1 + p.y] = s.y;
    ss[r2 + p.z] = s.z;
    ss[r3 + p.w] = s.w;
  } else {
    for (; e < E; ++e) ss[rp[dst[e]] + pos[e]] = src[e];
  }
}

__global__ __launch_bounds__(256) void block_sum_kernel(const int* __restrict__ cnt,
                                                        int* __restrict__ bsum, int N) {
  const int tid = threadIdx.x, lane = tid & 63, wid = tid >> 6;
  __shared__ int wt[4];
  int base = blockIdx.x * 2048 + tid * 8;
  int s = 0;
#pragma unroll
  for (int q = 0; q < 8; ++q) { int i = base + q; if (i < N) s += cnt[i]; }
#pragma unroll
  for (int off = 32; off; off >>= 1) s += __shfl_down(s, off);
  if (lane == 0) wt[wid] = s;
  __syncthreads();
  if (tid == 0) bsum[blockIdx.x] = wt[0] + wt[1] + wt[2] + wt[3];
}

__global__ __launch_bounds__(256) void scan_bsum_kernel(const int* __restrict__ bsum,
                                                        int* __restrict__ boff,
                                                        int NB, int E, int* __restrict__ rpN) {
  __shared__ int sh[256];
  const int tid = threadIdx.x;
  int v = (tid < NB) ? bsum[tid] : 0;
  sh[tid] = v;
  __syncthreads();
  for (int off = 1; off < 256; off <<= 1) {
    int t = (tid >= off) ? sh[tid - off] : 0;
    __syncthreads();
    sh[tid] += t;
    __syncthreads();
  }
  if (tid < NB) boff[tid] = sh[tid] - v;
  if (tid == 0) rpN[0] = E;
}

__global__ __launch_bounds__(256) void scan_apply_kernel(const int* __restrict__ cnt,
                                                         const int* __restrict__ boff,
                                                         int* __restrict__ rp,
                                                         float* __restrict__ dis, int N) {
  const int tid = threadIdx.x, lane = tid & 63, wid = tid >> 6;
  __shared__ int wtot[4], wexc[4];
  int base = blockIdx.x * 2048 + tid * 8;
  int v[8]; int s = 0;
#pragma unroll
  for (int q = 0; q < 8; ++q) { int i = base + q; int x = (i < N) ? cnt[i] : 0; v[q] = x; s += x; }
  int sc = s;
#pragma unroll
  for (int off = 1; off < 64; off <<= 1) { int t = __shfl_up(sc, off); if (lane >= off) sc += t; }
  if (lane == 63) wtot[wid] = sc;
  __syncthreads();
  if (tid == 0) { int r = 0; for (int wq = 0; wq < 4; ++wq) { wexc[wq] = r; r += wtot[wq]; } }
  __syncthreads();
  int thr = boff[blockIdx.x] + wexc[wid] + (sc - s);
#pragma unroll
  for (int q = 0; q < 8; ++q) {
    int i = base + q;
    if (i < N) { rp[i] = thr; dis[i] = rsqrtf((float)(v[q] + 1)); }
    thr += v[q];
  }
}

// ---------------- dtype conversion ----------------

__global__ __launch_bounds__(256) void cvt_x_kernel(const float* __restrict__ X,
                                                    _Float16* __restrict__ Xh, int total) {
  int i = (blockIdx.x * 256 + threadIdx.x) * 8;
  if (i + 8 <= total) {
    float4 a = *(const float4*)&X[i];
    float4 b = *(const float4*)&X[i + 4];
    half8_t o;
    o[0] = (_Float16)a.x; o[1] = (_Float16)a.y; o[2] = (_Float16)a.z; o[3] = (_Float16)a.w;
    o[4] = (_Float16)b.x; o[5] = (_Float16)b.y; o[6] = (_Float16)b.z; o[7] = (_Float16)b.w;
    *(half8_t*)&Xh[i] = o;
  } else {
    for (; i < total; ++i) Xh[i] = (_Float16)X[i];
  }
}

// Wt[c*K + k] = fp16(W[k*C + c])
__global__ __launch_bounds__(256) void cvt_wT_kernel(const float* __restrict__ W,
                                                     _Float16* __restrict__ Wt, int K, int C) {
  int i = blockIdx.x * 256 + threadIdx.x;
  if (i < K * C) {
    int k = i / C, c = i % C;
    Wt[(size_t)c * K + k] = (_Float16)W[i];
  }
}

// ---------------- MFMA GEMM: G = fp16( dis[row] * (Xh @ Wt^T) ), K=128 ----------------
// Xh: [N][128] fp16 row-major. Wt: [COUT][128] fp16 (= W transposed).
// Wave tile 64x64, WM x WN waves per block (256 threads = 4 waves).

template <int COUT, int WM, int WN>
__global__ __launch_bounds__(256) void mfma_gemm_kernel(const half8_t* __restrict__ Xh,
                                                        const half8_t* __restrict__ Wt,
                                                        const float* __restrict__ dis,
                                                        _Float16* __restrict__ G, int N) {
  const int wave = threadIdx.x >> 6;
  const int lane = threadIdx.x & 63;
  const int wm = wave / WN, wn = wave % WN;
  const int row0 = blockIdx.x * (WM * 64) + wm * 64;
  const int col0 = wn * 64;
  const int lr = lane & 15;   // A row / B col / D col
  const int lk = lane >> 4;   // k-block
  f32x4 acc[4][4];
#pragma unroll
  for (int r = 0; r < 4; ++r)
#pragma unroll
    for (int c = 0; c < 4; ++c) acc[r][c] = (f32x4){0.f, 0.f, 0.f, 0.f};

#pragma unroll
  for (int ks = 0; ks < 4; ++ks) {
    half8_t a[4], b[4];
#pragma unroll
    for (int r = 0; r < 4; ++r) {
      int row = row0 + r * 16 + lr;
      half8_t az = {};
      a[r] = (row < N) ? Xh[(size_t)row * 16 + ks * 4 + lk] : az;
    }
#pragma unroll
    for (int c = 0; c < 4; ++c) {
      int col = col0 + c * 16 + lr;
      b[c] = Wt[(size_t)col * 16 + ks * 4 + lk];
    }
#pragma unroll
    for (int r = 0; r < 4; ++r)
#pragma unroll
      for (int c = 0; c < 4; ++c)
        acc[r][c] = __builtin_amdgcn_mfma_f32_16x16x32_f16(a[r], b[c], acc[r][c], 0, 0, 0);
  }

#pragma unroll
  for (int r = 0; r < 4; ++r) {
#pragma unroll
    for (int q = 0; q < 4; ++q) {
      int row = row0 + r * 16 + lk * 4 + q;
      if (row < N) {
        float dv = dis[row];
#pragma unroll
        for (int c = 0; c < 4; ++c) {
          G[(size_t)row * COUT + col0 + c * 16 + lr] = (_Float16)(acc[r][c][q] * dv);
        }
      }
    }
  }
}

// ---------------- Aggregation: out[i] = dis[i]*(g[i] + sum g[src]) + b ----------------
// F=128: 4 groups of 16 lanes per wave, each group owns a node; 16B/lane row slices.

template <bool RELU>
__global__ __launch_bounds__(256) void agg128_kernel(const _Float16* __restrict__ G,
                                                     const int* __restrict__ rp,
                                                     const int* __restrict__ ss,
                                                     const float* __restrict__ dis,
                                                     const float* __restrict__ bias,
                                                     _Float16* __restrict__ H, int N) {
  const int wave = threadIdx.x >> 6;
  const int lane = threadIdx.x & 63;
  const int grp = lane >> 4;
  const int sub = lane & 15;
  const int w = blockIdx.x * 16 + wave * 4 + grp;
  if (w >= N) return;
  const int e0 = rp[w], e1 = rp[w + 1];
  float acc[8];
  half8_t sv = *(const half8_t*)&G[(size_t)w * 128 + sub * 8];
#pragma unroll
  for (int j = 0; j < 8; ++j) acc[j] = (float)sv[j];
  int e = e0;
  for (; e + 4 <= e1; e += 4) {
    int i0 = ss[e], i1 = ss[e + 1], i2 = ss[e + 2], i3 = ss[e + 3];
    half8_t v0 = *(const half8_t*)&G[(size_t)i0 * 128 + sub * 8];
    half8_t v1 = *(const half8_t*)&G[(size_t)i1 * 128 + sub * 8];
    half8_t v2 = *(const half8_t*)&G[(size_t)i2 * 128 + sub * 8];
    half8_t v3 = *(const half8_t*)&G[(size_t)i3 * 128 + sub * 8];
#pragma unroll
    for (int j = 0; j < 8; ++j)
      acc[j] += ((float)v0[j] + (float)v1[j]) + ((float)v2[j] + (float)v3[j]);
  }
  for (; e < e1; ++e) {
    half8_t v0 = *(const half8_t*)&G[(size_t)ss[e] * 128 + sub * 8];
#pragma unroll
    for (int j = 0; j < 8; ++j) acc[j] += (float)v0[j];
  }
  float d = dis[w];
  float4 b0 = *(const float4*)&bias[sub * 8];
  float4 b1 = *(const float4*)&bias[sub * 8 + 4];
  float bb[8] = {b0.x, b0.y, b0.z, b0.w, b1.x, b1.y, b1.z, b1.w};
  half8_t o;
#pragma unroll
  for (int j = 0; j < 8; ++j) {
    float v = d * acc[j] + bb[j];
    if (RELU) v = fmaxf(v, 0.f);
    o[j] = (_Float16)v;
  }
  *(half8_t*)&H[(size_t)w * 128 + sub * 8] = o;
}

// F=64: 8 groups of 8 lanes per wave; fp32 output.
__global__ __launch_bounds__(256) void agg64_kernel(const _Float16* __restrict__ G,
                                                    const int* __restrict__ rp,
                                                    const int* __restrict__ ss,
                                                    const float* __restrict__ dis,
                                                    const float* __restrict__ bias,
                                                    float* __restrict__ OUT, int N) {
  const int wave = threadIdx.x >> 6;
  const int lane = threadIdx.x & 63;
  const int grp = lane >> 3;
  const int sub = lane & 7;
  const int w = blockIdx.x * 32 + wave * 8 + grp;
  if (w >= N) return;
  const int e0 = rp[w], e1 = rp[w + 1];
  float acc[8];
  half8_t sv = *(const half8_t*)&G[(size_t)w * 64 + sub * 8];
#pragma unroll
  for (int j = 0; j < 8; ++j) acc[j] = (float)sv[j];
  int e = e0;
  for (; e + 4 <= e1; e += 4) {
    int i0 = ss[e], i1 = ss[e + 1], i2 = ss[e + 2], i3 = ss[e + 3];
    half8_t v0 = *(const half8_t*)&G[(size_t)i0 * 64 + sub * 8];
    half8_t v1 = *(const half8_t*)&G[(size_t)i1 * 64 + sub * 8];
    half8_t v2 = *(const half8_t*)&G[(size_t)i2 * 64 + sub * 8];
    half8_t v3 = *(const half8_t*)&G[(size_t)i3 * 64 + sub * 8];
#pragma unroll
    for (int j = 0; j < 8; ++j)
      acc[j] += ((float)v0[j] + (float)v1[j]) + ((float)v2[j] + (float)v3[j]);
  }
  for (; e < e1; ++e) {
    half8_t v0 = *(const half8_t*)&G[(size_t)ss[e] * 64 + sub * 8];
#pragma unroll
    for (int j = 0; j < 8; ++j) acc[j] += (float)v0[j];
  }
  float d = dis[w];
  float4 b0 = *(const float4*)&bias[sub * 8];
  float4 b1 = *(const float4*)&bias[sub * 8 + 4];
  float4 o0, o1;
  o0.x = d * acc[0] + b0.x; o0.y = d * acc[1] + b0.y;
  o0.z = d * acc[2] + b0.z; o0.w = d * acc[3] + b0.w;
  o1.x = d * acc[4] + b1.x; o1.y = d * acc[5] + b1.y;
  o1.z = d * acc[6] + b1.z; o1.w = d * acc[7] + b1.w;
  *(float4*)&OUT[(size_t)w * 64 + sub * 8] = o0;
  *(float4*)&OUT[(size_t)w * 64 + sub * 8 + 4] = o1;
}

// ---------------- launch ----------------

extern "C" void kernel_launch(void* const* d_in, const int* in_sizes, int n_in,
                              void* d_out, int out_size, void* d_ws, size_t ws_size,
                              hipStream_t stream) {
  const float* x  = (const float*)d_in[0];
  const int*   ei = (const int*)d_in[1];
  const float* W1 = (const float*)d_in[2];
  const float* b1 = (const float*)d_in[3];
  const float* W2 = (const float*)d_in[4];
  const float* b2 = (const float*)d_in[5];
  const float* W3 = (const float*)d_in[6];
  const float* b3 = (const float*)d_in[7];

  const int inC = in_sizes[2] / in_sizes[3];  // 128
  const int hid = in_sizes[3];                // 128
  const int N = in_sizes[0] / inC;            // 50000
  const int E = in_sizes[1] / 2;              // 800000
  const int outC = in_sizes[6] / hid;         // 64

  auto align256 = [](size_t v) { return (v + 255) & ~(size_t)255; };
  char* p = (char*)d_ws;
  int* cnt = (int*)p;   p += align256((size_t)N * 4);
  int* rp  = (int*)p;   p += align256((size_t)(N + 1) * 4);
  int* ss  = (int*)p;   p += align256((size_t)E * 4);
  int* pos = (int*)p;   p += align256((size_t)E * 4);
  float* dis = (float*)p; p += align256((size_t)N * 4);
  _Float16* xh = (_Float16*)p; p += align256((size_t)N * 128 * 2);
  _Float16* g  = (_Float16*)p; p += align256((size_t)N * 128 * 2);  // also reused for layer-3 (64-wide)
  _Float16* hh = (_Float16*)p; p += align256((size_t)N * 128 * 2);
  _Float16* wt1 = (_Float16*)p; p += align256((size_t)128 * 128 * 2);
  _Float16* wt2 = (_Float16*)p; p += align256((size_t)128 * 128 * 2);
  _Float16* wt3 = (_Float16*)p; p += align256((size_t)128 * 64 * 2);
  int* bsum = (int*)p;  p += align256(1024 * 4);
  int* boff = (int*)p;  p += align256(1024 * 4);

  const int* srcv = ei;
  const int* dstv = ei + E;

  const int NB = (N + 2047) / 2048;
  const int eB4 = (E / 4 + 255) / 256;

  // CSR build
  hipMemsetAsync(cnt, 0, (size_t)N * 4, stream);
  countpos_kernel<<<eB4, 256, 0, stream>>>(dstv, cnt, pos, E);
  block_sum_kernel<<<NB, 256, 0, stream>>>(cnt, bsum, N);
  scan_bsum_kernel<<<1, 256, 0, stream>>>(bsum, boff, NB, E, rp + N);
  scan_apply_kernel<<<NB, 256, 0, stream>>>(cnt, boff, rp, dis, N);
  place_kernel<<<eB4, 256, 0, stream>>>(srcv, dstv, pos, rp, ss, E);

  // fp16 conversions
  cvt_x_kernel<<<(N * 128 / 8 + 255) / 256, 256, 0, stream>>>(x, xh, N * 128);
  cvt_wT_kernel<<<(128 * 128 + 255) / 256, 256, 0, stream>>>(W1, wt1, 128, 128);
  cvt_wT_kernel<<<(128 * 128 + 255) / 256, 256, 0, stream>>>(W2, wt2, 128, 128);
  cvt_wT_kernel<<<(128 * 64 + 255) / 256, 256, 0, stream>>>(W3, wt3, 128, 64);

  const int g128B = (N + 127) / 128;   // 391
  const int g64B  = (N + 255) / 256;   // 196
  const int a128B = (N + 15) / 16;     // 3125
  const int a64B  = (N + 31) / 32;     // 1563

  // layer 1: 128 -> 128, relu
  mfma_gemm_kernel<128, 2, 2><<<g128B, 256, 0, stream>>>((const half8_t*)xh, (const half8_t*)wt1, dis, g, N);
  agg128_kernel<true><<<a128B, 256, 0, stream>>>(g, rp, ss, dis, b1, hh, N);
  // layer 2: 128 -> 128, relu
  mfma_gemm_kernel<128, 2, 2><<<g128B, 256, 0, stream>>>((const half8_t*)hh, (const half8_t*)wt2, dis, g, N);
  agg128_kernel<true><<<a128B, 256, 0, stream>>>(g, rp, ss, dis, b2, hh, N);
  // layer 3: 128 -> 64, no relu (reuse g buffer for 64-wide output)
  mfma_gemm_kernel<64, 4, 1><<<g64B, 256, 0, stream>>>((const half8_t*)hh, (const half8_t*)wt3, dis, g, N);
  agg64_kernel<<<a64B, 256, 0, stream>>>(g, rp, ss, dis, b3, (float*)d_out, N);
}